// Round 3
// baseline (1796.048 us; speedup 1.0000x reference)
//
#include <hip/hip_runtime.h>

typedef unsigned short u16;
typedef unsigned int   u32;

#define N_MESH 50000
#define RA     40      // R*A
#define F_     32
#define OT     256     // O*T
#define KSELF  1280    // RA*F
#define KTOT   1312    // RA*F + F
#define GN     8       // mesh rows per block (50000 = 8*6250 exact)
#define NBLK   6250

// Device-global scratch / flags (no dependence on ws_size).
__device__ __align__(16) float g_wefft[KTOT * OT];  // [k][c] fp32, 1.34 MB
__device__ int g_isf32;

__device__ __forceinline__ float bf2f(u16 u) {
    union { u32 i; float f; } v; v.i = ((u32)u) << 16; return v.f;
}
__device__ __forceinline__ u16 f2bf(float f) {
    union { float f; u32 i; } v; v.f = f; u32 u = v.i;
    return (u16)((u + 0x7FFFu + ((u >> 16) & 1u)) >> 16);   // RNE
}
// Element load honoring runtime dtype flag (i is an ELEMENT index).
__device__ __forceinline__ float ld(const void* p, int i, int isf32) {
    return isf32 ? ((const float*)p)[i] : bf2f(((const u16*)p)[i]);
}

// ---------------------------------------------------------------------------
// Dtype probe: decode first 4096 u16 of mesh_signal as bf16. If the buffer is
// fp32, ~25% decode to wild exponents (>1e6 or subnormal); if bf16 N(0,1),
// none do. Deterministic, same work every call.
// ---------------------------------------------------------------------------
__global__ void detect_kernel(const void* mesh) {
    if (blockIdx.x == 0 && threadIdx.x == 0) {
        const u16* p = (const u16*)mesh;
        int weird = 0;
        for (int i = 0; i < 4096; ++i) {
            float v = bf2f(p[i]);
            float a = v < 0.f ? -v : v;
            if (!(a <= 1.0e6f)) ++weird;                 // huge or NaN
            else if (a > 0.f && a < 1.0e-30f) ++weird;   // subnormal-ish
        }
        g_isf32 = (weird > 100) ? 1 : 0;
    }
}

// ---------------------------------------------------------------------------
// WeffT[k][c] fp32:
//   k <  1280 : sum_ra kernel[ra][xy] * W_neighbor[t][r][(a+o)&7][f]
//               (xy = k>>5, f = k&31, c = o*32+t)
//   k >= 1280 : W_self[t][k-1280]
// ---------------------------------------------------------------------------
__global__ void weff_kernel(const void* __restrict__ Wn,
                            const void* __restrict__ Wself,
                            const void* __restrict__ ker) {
    int e = blockIdx.x * blockDim.x + threadIdx.x;
    if (e >= OT * KTOT) return;
    int isf32 = g_isf32;
    int c = e / KTOT;
    int k = e - c * KTOT;
    int o = c >> 5, t = c & 31;
    float acc = 0.f;
    if (k < KSELF) {
        int xy = k >> 5, f = k & 31;
        for (int ra = 0; ra < RA; ++ra) {
            int r = ra >> 3, a = ra & 7;
            int a2 = (a + o) & 7;
            acc += ld(ker, ra * RA + xy, isf32) *
                   ld(Wn, t * (5 * 8 * F_) + r * (8 * F_) + a2 * F_ + f, isf32);
        }
    } else {
        acc = ld(Wself, t * F_ + (k - KSELF), isf32);
    }
    g_wefft[k * OT + c] = acc;
}

// ---------------------------------------------------------------------------
// Main: per block, stage GN=8 interp rows (fp32, [k][n] layout) in LDS, then
// thread c computes out[n0+r][c] = relu(sum_k A[k][r]*WeffT[k][c] + bias[c&31]).
// ---------------------------------------------------------------------------
__global__ __launch_bounds__(256)
void ConvIntrinsic_17102559772776_kernel(const void* __restrict__ mesh,
                                         const void* __restrict__ bary,
                                         const void* __restrict__ bias,
                                         void* __restrict__ out) {
    __shared__ __align__(16) float A_lds[KTOT * GN];   // 42 KB

    const int tid = threadIdx.x;
    const int n0  = blockIdx.x * GN;
    const int isf32 = g_isf32;

    // ---- phase 1: cooperative gather + barycentric interp -> LDS ----
    for (int task = tid; task < GN * (RA + 1); task += 256) {
        int n  = task / (RA + 1);
        int kc = task - n * (RA + 1);
        int gn = n0 + n;
        if (kc < RA) {
            int base = gn * (RA * 6) + kc * 6;   // element index of (idx,w)*3
            float fi0 = ld(bary, base + 0, isf32), w0 = ld(bary, base + 1, isf32);
            float fi1 = ld(bary, base + 2, isf32), w1 = ld(bary, base + 3, isf32);
            float fi2 = ld(bary, base + 4, isf32), w2 = ld(bary, base + 5, isf32);
            int i0 = (int)fi0, i1 = (int)fi1, i2 = (int)fi2;
            i0 = i0 < 0 ? 0 : (i0 > N_MESH - 1 ? N_MESH - 1 : i0);   // jax gather clamps
            i1 = i1 < 0 ? 0 : (i1 > N_MESH - 1 ? N_MESH - 1 : i1);
            i2 = i2 < 0 ? 0 : (i2 > N_MESH - 1 ? N_MESH - 1 : i2);
            for (int f = 0; f < F_; ++f) {
                float v = w0 * ld(mesh, i0 * F_ + f, isf32)
                        + w1 * ld(mesh, i1 * F_ + f, isf32)
                        + w2 * ld(mesh, i2 * F_ + f, isf32);
                A_lds[(kc * F_ + f) * GN + n] = v;
            }
        } else {
            for (int f = 0; f < F_; ++f)
                A_lds[(KSELF + f) * GN + n] = ld(mesh, gn * F_ + f, isf32);
        }
    }
    __syncthreads();

    // ---- phase 2: thread c = tid does the K=1312 dot products ----
    float acc[GN];
    #pragma unroll
    for (int r = 0; r < GN; ++r) acc[r] = 0.f;

    const float* __restrict__ wt = g_wefft + tid;   // column c, stride OT
    #pragma unroll 4
    for (int k = 0; k < KTOT; ++k) {
        float b = wt[k * OT];
        const float4* ap = (const float4*)(A_lds + k * GN);
        float4 x = ap[0];
        float4 y = ap[1];
        acc[0] += x.x * b; acc[1] += x.y * b; acc[2] += x.z * b; acc[3] += x.w * b;
        acc[4] += y.x * b; acc[5] += y.y * b; acc[6] += y.z * b; acc[7] += y.w * b;
    }

    float bv = ld(bias, tid & 31, isf32);
    #pragma unroll
    for (int r = 0; r < GN; ++r) {
        float v = acc[r] + bv;
        v = v > 0.f ? v : 0.f;
        int oi = (n0 + r) * OT + tid;
        if (isf32) ((float*)out)[oi] = v;
        else       ((u16*)out)[oi]   = f2bf(v);
    }
}

extern "C" void kernel_launch(void* const* d_in, const int* in_sizes, int n_in,
                              void* d_out, int out_size, void* d_ws, size_t ws_size,
                              hipStream_t stream) {
    const void* mesh  = d_in[0];
    const void* bary  = d_in[1];
    const void* Wself = d_in[2];
    const void* Wn    = d_in[3];
    const void* bias  = d_in[4];
    const void* ker   = d_in[5];
    (void)in_sizes; (void)n_in; (void)out_size; (void)d_ws; (void)ws_size;

    detect_kernel<<<1, 1, 0, stream>>>(mesh);

    {
        int total  = OT * KTOT;
        int blocks = (total + 255) / 256;
        weff_kernel<<<blocks, 256, 0, stream>>>(Wn, Wself, ker);
    }

    ConvIntrinsic_17102559772776_kernel<<<NBLK, 256, 0, stream>>>(mesh, bary, bias, d_out);
}